// Round 4
// baseline (1154.789 us; speedup 1.0000x reference)
//
#include <hip/hip_runtime.h>
#include <hip/hip_bf16.h>

#define N_NODES 20000
#define N_EDGES 320000
#define D 128

typedef __attribute__((ext_vector_type(8))) short short8;
typedef __attribute__((ext_vector_type(4))) float f32x4;

__device__ __forceinline__ float sigmoid_f(float z) { return 1.f / (1.f + __expf(-z)); }
__device__ __forceinline__ float silu_f(float z) { return z * sigmoid_f(z); }
__device__ __forceinline__ short f2bf(float f) {
    union { float f; unsigned u; } a; a.f = f;
    unsigned r = a.u + 0x7fff + ((a.u >> 16) & 1);   // RNE
    return (short)(r >> 16);
}
__device__ __forceinline__ float bf2f(short s) {
    union { unsigned u; float f; } a; a.u = ((unsigned)(unsigned short)s) << 16;
    return a.f;
}

// ---------------------------------------------------------------------------
// counting sort of edges by src (edge_index is invariant across layers/calls)
// ---------------------------------------------------------------------------
__global__ void hist_kernel(const int* __restrict__ ei, int* __restrict__ hist) {
    int e = blockIdx.x * 256 + threadIdx.x;
    if (e < N_EDGES) atomicAdd(&hist[ei[e]], 1);
}

__global__ void scan_kernel(const int* __restrict__ hist, int* __restrict__ offs) {
    __shared__ int part[1024];
    __shared__ int ppre[1024];
    int t = threadIdx.x;
    int base = t * 20;
    int s = 0;
    for (int j = 0; j < 20; j++) { int i = base + j; if (i < N_NODES) s += hist[i]; }
    part[t] = s;
    __syncthreads();
    if (t == 0) { int acc = 0; for (int i = 0; i < 1024; i++) { ppre[i] = acc; acc += part[i]; } }
    __syncthreads();
    int run = ppre[t];
    for (int j = 0; j < 20; j++) {
        int i = base + j;
        if (i < N_NODES) { offs[i] = run; run += hist[i]; }
    }
}

__global__ void scatter_kernel(const int* __restrict__ ei, const int* __restrict__ offs,
                               int* __restrict__ cursor,
                               int* __restrict__ es, int* __restrict__ ed) {
    int e = blockIdx.x * 256 + threadIdx.x;
    if (e < N_EDGES) {
        int s = ei[e], d = ei[N_EDGES + e];
        int p = offs[s] + atomicAdd(&cursor[s], 1);
        es[p] = s; ed[p] = d;
    }
}

// ---------------------------------------------------------------------------
// gsum = sum over all edges of ||x[src]-x[dst]||^2
// ---------------------------------------------------------------------------
__global__ void precompute_kernel(const int* __restrict__ es, const int* __restrict__ ed,
                                  const float* __restrict__ x,
                                  float* __restrict__ gsum) {
    int e = blockIdx.x * blockDim.x + threadIdx.x;
    float local = 0.f;
    if (e < N_EDGES) {
        int s = es[e];
        int d = ed[e];
        float dx = x[s * 3 + 0] - x[d * 3 + 0];
        float dy = x[s * 3 + 1] - x[d * 3 + 1];
        float dz = x[s * 3 + 2] - x[d * 3 + 2];
        local = dx * dx + dy * dy + dz * dz;
    }
    #pragma unroll
    for (int o = 32; o > 0; o >>= 1) local += __shfl_down(local, o, 64);
    if ((threadIdx.x & 63) == 0) atomicAdd(gsum, local);
}

// ---------------------------------------------------------------------------
// transpose+bf16-convert the per-layer weights.
// WcatT[1024][128] row blocks (256 each): [m_src | x_src | m_dst | x_dst]
//   = [Wm1[0:128]^T | Wx1[0:128]^T | Wm1[128:256]^T | Wx1[128:256]^T]
// Wm2T[128][256], Wh1T[256][256], Wh2T[128][256], Wx2T[16][256] (rows 3-15 zero)
// ---------------------------------------------------------------------------
__global__ void prep_weights(const float* __restrict__ Wm1, const float* __restrict__ Wx1,
                             const float* __restrict__ Wm2, const float* __restrict__ Wh1,
                             const float* __restrict__ Wh2, const float* __restrict__ Wx2,
                             short* __restrict__ WcatT, short* __restrict__ Wm2T,
                             short* __restrict__ Wh1T, short* __restrict__ Wh2T,
                             short* __restrict__ Wx2T) {
    int idx = blockIdx.x * 256 + threadIdx.x;   // 0 .. 266239
    if (idx < 131072) {
        int seg = idx >> 15, r = idx & 32767, k = r >> 8, c = r & 255;
        const float* s = (seg == 0) ? Wm1 : (seg == 1) ? Wx1
                        : (seg == 2) ? Wm1 + 128 * 256 : Wx1 + 128 * 256;
        WcatT[(size_t)(seg * 256 + c) * 128 + k] = f2bf(s[k * 256 + c]);
    } else if (idx < 163840) {
        int r = idx - 131072, k = r >> 7, c = r & 127;
        Wm2T[c * 256 + k] = f2bf(Wm2[k * 128 + c]);
    } else if (idx < 229376) {
        int r = idx - 163840, k = r >> 8, c = r & 255;
        Wh1T[c * 256 + k] = f2bf(Wh1[k * 256 + c]);
    } else if (idx < 262144) {
        int r = idx - 229376, k = r >> 7, c = r & 127;
        Wh2T[c * 256 + k] = f2bf(Wh2[k * 128 + c]);
    } else {
        int r = idx - 262144, c = r >> 8, k = r & 255;
        Wx2T[c * 256 + k] = (c < 3) ? f2bf(Wx2[k * 3 + c]) : (short)0;
    }
}

// ---------------------------------------------------------------------------
// T[n][1024] (bf16) = h[n][0:128] @ WcatT^T   (MFMA 16x16x32 bf16)
// ---------------------------------------------------------------------------
__global__ __launch_bounds__(256, 4) void tgemm_kernel(const float* __restrict__ h,
        const short* __restrict__ WcatT, short* __restrict__ T) {
    int tid = threadIdx.x, w = tid >> 6, l = tid & 63;
    int l15 = l & 15, kg = l >> 4;
    int rowbase = blockIdx.x * 64 + w * 16;
    int cg = blockIdx.y;                       // 0..3
    int arow = rowbase + l15; if (arow >= N_NODES) arow = N_NODES - 1;
    f32x4 acc[16];
    #pragma unroll
    for (int ct = 0; ct < 16; ct++) acc[ct] = (f32x4){0.f, 0.f, 0.f, 0.f};
    #pragma unroll
    for (int ks = 0; ks < 4; ks++) {
        int kb = ks * 32 + kg * 8;
        const f32x4* hp = (const f32x4*)(h + (size_t)arow * 128 + kb);
        f32x4 h0 = hp[0], h1 = hp[1];
        short8 a;
        a[0] = f2bf(h0.x); a[1] = f2bf(h0.y); a[2] = f2bf(h0.z); a[3] = f2bf(h0.w);
        a[4] = f2bf(h1.x); a[5] = f2bf(h1.y); a[6] = f2bf(h1.z); a[7] = f2bf(h1.w);
        #pragma unroll
        for (int ct = 0; ct < 16; ct++) {
            short8 b = *(const short8*)(WcatT + (size_t)(cg * 256 + ct * 16 + l15) * 128 + kb);
            acc[ct] = __builtin_amdgcn_mfma_f32_16x16x32_bf16(a, b, acc[ct], 0, 0, 0);
        }
    }
    #pragma unroll
    for (int ct = 0; ct < 16; ct++) {
        #pragma unroll
        for (int r = 0; r < 4; r++) {
            int node = rowbase + kg * 4 + r;
            if (node < N_NODES)
                T[(size_t)node * 1024 + cg * 256 + ct * 16 + l15] = f2bf(acc[ct][r]);
        }
    }
}

// ---------------------------------------------------------------------------
// fused edge kernel on src-sorted edges. 64 edges/block, 4 waves, 16 edges/wave.
// m: z = T[s][m_src] + T[d][m_dst] + d2*w + b -> silu -> MFMA @Wm2T -> gate
//    -> run-dedup'd atomic scatter to agg_h
// x: z -> silu -> MFMA @Wx2T(3 cols) -> diff*px*invg atomic scatter to aggx
// ---------------------------------------------------------------------------
__global__ __launch_bounds__(256, 6) void edge_kernel(
    const int* __restrict__ es, const int* __restrict__ ed,
    const short* __restrict__ T, const float* __restrict__ xc,
    const float* __restrict__ gsum,
    const float* __restrict__ Wm1r, const float* __restrict__ bm1,
    const short* __restrict__ Wm2T, const float* __restrict__ bm2,
    const float* __restrict__ Wa, const float* __restrict__ ba,
    const float* __restrict__ Wx1r, const float* __restrict__ bx1,
    const short* __restrict__ Wx2T, const float* __restrict__ bx2,
    float* __restrict__ agg_h, float* __restrict__ aggx) {
    __shared__ float sdiff[64][4];
    int tid = threadIdx.x, w = tid >> 6, l = tid & 63;
    int l15 = l & 15, kg = l >> 4;
    int ebase = blockIdx.x * 64 + w * 16;
    int e = ebase + l15;
    int src = es[e], dst = ed[e];
    float dfx = xc[src * 3 + 0] - xc[dst * 3 + 0];
    float dfy = xc[src * 3 + 1] - xc[dst * 3 + 1];
    float dfz = xc[src * 3 + 2] - xc[dst * 3 + 2];
    float d2v = dfx * dfx + dfy * dfy + dfz * dfz;
    if (kg == 0) {
        sdiff[w * 16 + l15][0] = dfx;
        sdiff[w * 16 + l15][1] = dfy;
        sdiff[w * 16 + l15][2] = dfz;
    }
    __syncthreads();

    int srow[4];
    #pragma unroll
    for (int r = 0; r < 4; r++) srow[r] = es[ebase + kg * 4 + r];

    // ---- m branch ----
    f32x4 acc[8];
    #pragma unroll
    for (int ct = 0; ct < 8; ct++) { float bv = bm2[ct * 16 + l15]; acc[ct] = (f32x4){bv, bv, bv, bv}; }
    #pragma unroll
    for (int ks = 0; ks < 8; ks++) {
        int cb = ks * 32 + kg * 8;
        short8 ts = *(const short8*)(T + (size_t)src * 1024 + cb);          // m_src
        short8 td = *(const short8*)(T + (size_t)dst * 1024 + 512 + cb);    // m_dst
        f32x4 w0 = ((const f32x4*)(Wm1r + cb))[0], w1 = ((const f32x4*)(Wm1r + cb))[1];
        f32x4 b0 = ((const f32x4*)(bm1 + cb))[0], b1 = ((const f32x4*)(bm1 + cb))[1];
        float wv[8], bv[8];
        *(f32x4*)&wv[0] = w0; *(f32x4*)&wv[4] = w1;
        *(f32x4*)&bv[0] = b0; *(f32x4*)&bv[4] = b1;
        short8 a;
        #pragma unroll
        for (int i = 0; i < 8; i++) {
            float z = bf2f(ts[i]) + bf2f(td[i]) + d2v * wv[i] + bv[i];
            a[i] = f2bf(silu_f(z));
        }
        #pragma unroll
        for (int ct = 0; ct < 8; ct++) {
            short8 b = *(const short8*)(Wm2T + (size_t)(ct * 16 + l15) * 256 + cb);
            acc[ct] = __builtin_amdgcn_mfma_f32_16x16x32_bf16(a, b, acc[ct], 0, 0, 0);
        }
    }
    // gate: s = m @ Wa + ba
    float part[4] = {0.f, 0.f, 0.f, 0.f};
    #pragma unroll
    for (int ct = 0; ct < 8; ct++) {
        float wa = Wa[ct * 16 + l15];
        #pragma unroll
        for (int r = 0; r < 4; r++) part[r] += acc[ct][r] * wa;
    }
    #pragma unroll
    for (int m = 1; m < 16; m <<= 1) {
        #pragma unroll
        for (int r = 0; r < 4; r++) part[r] += __shfl_xor(part[r], m, 64);
    }
    float ba0 = ba[0];
    float gate[4];
    #pragma unroll
    for (int r = 0; r < 4; r++) gate[r] = sigmoid_f(part[r] + ba0);
    // scatter with run-length dedup over the 4 rows (sorted => runs common)
    #pragma unroll
    for (int ct = 0; ct < 8; ct++) {
        int c = ct * 16 + l15;
        float run = acc[ct][0] * gate[0];
        #pragma unroll
        for (int r = 1; r < 4; r++) {
            float v = acc[ct][r] * gate[r];
            if (srow[r] == srow[r - 1]) {
                run += v;
            } else {
                atomicAdd(&agg_h[(size_t)srow[r - 1] * 128 + c], run);
                run = v;
            }
        }
        atomicAdd(&agg_h[(size_t)srow[3] * 128 + c], run);
    }

    // ---- x branch (MFMA with 3-col padded Wx2T) ----
    float bxi = (l15 < 3) ? bx2[l15] : 0.f;
    f32x4 accx = (f32x4){bxi, bxi, bxi, bxi};
    #pragma unroll
    for (int ks = 0; ks < 8; ks++) {
        int cb = ks * 32 + kg * 8;
        short8 ts = *(const short8*)(T + (size_t)src * 1024 + 256 + cb);    // x_src
        short8 td = *(const short8*)(T + (size_t)dst * 1024 + 768 + cb);    // x_dst
        f32x4 w0 = ((const f32x4*)(Wx1r + cb))[0], w1 = ((const f32x4*)(Wx1r + cb))[1];
        f32x4 b0 = ((const f32x4*)(bx1 + cb))[0], b1 = ((const f32x4*)(bx1 + cb))[1];
        float wv[8], bv[8];
        *(f32x4*)&wv[0] = w0; *(f32x4*)&wv[4] = w1;
        *(f32x4*)&bv[0] = b0; *(f32x4*)&bv[4] = b1;
        short8 a;
        #pragma unroll
        for (int i = 0; i < 8; i++) {
            float z = bf2f(ts[i]) + bf2f(td[i]) + d2v * wv[i] + bv[i];
            a[i] = f2bf(silu_f(z));
        }
        short8 b = *(const short8*)(Wx2T + (size_t)l15 * 256 + cb);
        accx = __builtin_amdgcn_mfma_f32_16x16x32_bf16(a, b, accx, 0, 0, 0);
    }
    if (l15 < 3) {
        float gn = sqrtf(gsum[0]);
        float invg = 1.f / (gn + 1.f);
        #pragma unroll
        for (int r = 0; r < 4; r++) {
            float df = sdiff[w * 16 + kg * 4 + r][l15];
            atomicAdd(&aggx[(size_t)srow[r] * 3 + l15], df * accx[r] * invg);
        }
    }
}

// ---------------------------------------------------------------------------
// node kernel (MFMA): new_h = silu(cat(h,agg)@Wh1+bh1)@Wh2+bh2 ; new_x = x+aggx
// ---------------------------------------------------------------------------
__global__ __launch_bounds__(256, 4) void node_kernel(
    const float* __restrict__ hc, const float* __restrict__ xc,
    const float* __restrict__ agg_h, const float* __restrict__ aggx,
    const short* __restrict__ Wh1T, const float* __restrict__ bh1,
    const short* __restrict__ Wh2T, const float* __restrict__ bh2,
    float* __restrict__ ho, float* __restrict__ xo) {
    __shared__ short sH[64][264];
    int tid = threadIdx.x, w = tid >> 6, l = tid & 63;
    int l15 = l & 15, kg = l >> 4;
    int nbase = blockIdx.x * 64;
    int arow = nbase + w * 16 + l15;
    int arc = (arow < N_NODES) ? arow : (N_NODES - 1);

    f32x4 acc1[16];
    #pragma unroll
    for (int ct = 0; ct < 16; ct++) { float bv = bh1[ct * 16 + l15]; acc1[ct] = (f32x4){bv, bv, bv, bv}; }
    #pragma unroll
    for (int ks = 0; ks < 8; ks++) {
        int kb = ks * 32 + kg * 8;
        const float* sp = (kb < 128) ? (hc + (size_t)arc * 128 + kb)
                                     : (agg_h + (size_t)arc * 128 + (kb - 128));
        f32x4 h0 = ((const f32x4*)sp)[0], h1 = ((const f32x4*)sp)[1];
        short8 a;
        a[0] = f2bf(h0.x); a[1] = f2bf(h0.y); a[2] = f2bf(h0.z); a[3] = f2bf(h0.w);
        a[4] = f2bf(h1.x); a[5] = f2bf(h1.y); a[6] = f2bf(h1.z); a[7] = f2bf(h1.w);
        #pragma unroll
        for (int ct = 0; ct < 16; ct++) {
            short8 b = *(const short8*)(Wh1T + (size_t)(ct * 16 + l15) * 256 + kb);
            acc1[ct] = __builtin_amdgcn_mfma_f32_16x16x32_bf16(a, b, acc1[ct], 0, 0, 0);
        }
    }
    #pragma unroll
    for (int ct = 0; ct < 16; ct++)
        #pragma unroll
        for (int r = 0; r < 4; r++)
            sH[w * 16 + kg * 4 + r][ct * 16 + l15] = f2bf(silu_f(acc1[ct][r]));
    __syncthreads();

    f32x4 acc2[8];
    #pragma unroll
    for (int ct = 0; ct < 8; ct++) { float bv = bh2[ct * 16 + l15]; acc2[ct] = (f32x4){bv, bv, bv, bv}; }
    #pragma unroll
    for (int ks = 0; ks < 8; ks++) {
        int kb = ks * 32 + kg * 8;
        short8 a = *(const short8*)&sH[w * 16 + l15][kb];
        #pragma unroll
        for (int ct = 0; ct < 8; ct++) {
            short8 b = *(const short8*)(Wh2T + (size_t)(ct * 16 + l15) * 256 + kb);
            acc2[ct] = __builtin_amdgcn_mfma_f32_16x16x32_bf16(a, b, acc2[ct], 0, 0, 0);
        }
    }
    #pragma unroll
    for (int ct = 0; ct < 8; ct++)
        #pragma unroll
        for (int r = 0; r < 4; r++) {
            int node = nbase + w * 16 + kg * 4 + r;
            if (node < N_NODES) ho[(size_t)node * 128 + ct * 16 + l15] = acc2[ct][r];
        }

    if (tid < 192) {
        int nn = tid / 3, c = tid - nn * 3;
        int node = nbase + nn;
        if (node < N_NODES)
            xo[(size_t)node * 3 + c] = xc[(size_t)node * 3 + c] + aggx[(size_t)node * 3 + c];
    }
}

// ---------------------------------------------------------------------------
extern "C" void kernel_launch(void* const* d_in, const int* in_sizes, int n_in,
                              void* d_out, int out_size, void* d_ws, size_t ws_size,
                              hipStream_t stream) {
    const int* ei = (const int*)d_in[0];
    const float* h_in = (const float*)d_in[1];
    const float* x_in = (const float*)d_in[2];
    const float* Wm1 = (const float*)d_in[3];
    const float* bm1 = (const float*)d_in[4];
    const float* Wm2 = (const float*)d_in[5];
    const float* bm2 = (const float*)d_in[6];
    const float* Wx1 = (const float*)d_in[7];
    const float* bx1 = (const float*)d_in[8];
    const float* Wx2 = (const float*)d_in[9];
    const float* bx2 = (const float*)d_in[10];
    const float* Wh1 = (const float*)d_in[11];
    const float* bh1 = (const float*)d_in[12];
    const float* Wh2 = (const float*)d_in[13];
    const float* bh2 = (const float*)d_in[14];
    const float* Wa = (const float*)d_in[15];
    const float* ba = (const float*)d_in[16];

    // workspace ~54.8 MiB (< 64 MiB budget)
    char* wsb = (char*)d_ws;
    short* T      = (short*)wsb;  wsb += (size_t)N_NODES * 1024 * 2;
    short* WcatT  = (short*)wsb;  wsb += (size_t)1024 * 128 * 2;
    short* Wm2T   = (short*)wsb;  wsb += (size_t)128 * 256 * 2;
    short* Wh1T   = (short*)wsb;  wsb += (size_t)256 * 256 * 2;
    short* Wh2T   = (short*)wsb;  wsb += (size_t)128 * 256 * 2;
    short* Wx2T   = (short*)wsb;  wsb += (size_t)16 * 256 * 2;
    float* agg_h  = (float*)wsb;  wsb += (size_t)N_NODES * 128 * 4;
    float* aggx   = (float*)wsb;  wsb += (size_t)N_NODES * 3 * 4;
    int*   es     = (int*)wsb;    wsb += (size_t)N_EDGES * 4;
    int*   ed     = (int*)wsb;    wsb += (size_t)N_EDGES * 4;
    int*   hist   = (int*)wsb;    wsb += (size_t)N_NODES * 4;
    int*   cursor = (int*)wsb;    wsb += (size_t)N_NODES * 4;
    float* gsum   = (float*)wsb;  wsb += 16;
    int*   offs   = (int*)wsb;    wsb += (size_t)(N_NODES + 16) * 4;

    float* h_out_f = (float*)d_out;
    float* x_out_f = h_out_f + (size_t)N_NODES * D;

    // ---- sort edges by src (once per call) ----
    hipMemsetAsync(hist, 0, sizeof(int) * N_NODES, stream);
    hipMemsetAsync(cursor, 0, sizeof(int) * N_NODES, stream);
    hist_kernel<<<(N_EDGES + 255) / 256, 256, 0, stream>>>(ei, hist);
    scan_kernel<<<1, 1024, 0, stream>>>(hist, offs);
    scatter_kernel<<<(N_EDGES + 255) / 256, 256, 0, stream>>>(ei, offs, cursor, es, ed);

    for (int l = 0; l < 2; l++) {
        const float* hc = (l == 0) ? h_in : h_out_f;   // layer-0 output staged in d_out
        const float* xc = (l == 0) ? x_in : x_out_f;
        float* ho = h_out_f;
        float* xo = x_out_f;

        const float* Wm1_l = Wm1 + (size_t)l * 257 * 256;
        const float* Wx1_l = Wx1 + (size_t)l * 257 * 256;

        hipMemsetAsync(gsum, 0, sizeof(float), stream);
        hipMemsetAsync(agg_h, 0, sizeof(float) * (size_t)N_NODES * 128, stream);
        hipMemsetAsync(aggx, 0, sizeof(float) * (size_t)N_NODES * 3, stream);

        prep_weights<<<1040, 256, 0, stream>>>(
            Wm1_l, Wx1_l, Wm2 + (size_t)l * 256 * 128,
            Wh1 + (size_t)l * 256 * 256, Wh2 + (size_t)l * 256 * 128,
            Wx2 + (size_t)l * 256 * 3,
            WcatT, Wm2T, Wh1T, Wh2T, Wx2T);

        precompute_kernel<<<(N_EDGES + 255) / 256, 256, 0, stream>>>(es, ed, xc, gsum);

        tgemm_kernel<<<dim3((N_NODES + 63) / 64, 4), 256, 0, stream>>>(hc, WcatT, T);

        edge_kernel<<<N_EDGES / 64, 256, 0, stream>>>(
            es, ed, T, xc, gsum,
            Wm1_l + 256 * 256, bm1 + (size_t)l * 256,
            Wm2T, bm2 + (size_t)l * 128,
            Wa + (size_t)l * 128, ba + l,
            Wx1_l + 256 * 256, bx1 + (size_t)l * 256,
            Wx2T, bx2 + (size_t)l * 3,
            agg_h, aggx);

        node_kernel<<<(N_NODES + 63) / 64, 256, 0, stream>>>(
            hc, xc, agg_h, aggx,
            Wh1T, bh1 + (size_t)l * 256,
            Wh2T, bh2 + (size_t)l * 128,
            ho, xo);
    }
}